// Round 4
// baseline (467.197 us; speedup 1.0000x reference)
//
#include <hip/hip_runtime.h>

// Multi-step integrate-and-fire (T=16 scan over independent elements).
// x_seq: (16, 32, 128, 32, 32) fp32 -> spikes same shape.
// R1/R3: load->wait->store per t-step left only 2 loads in flight/wave
//   (VGPR=28); latency-bound at 3.0 TB/s effective, HBM 30%, VALU 3%.
// R4 fix: addresses are t-independent -> issue ALL 16 plane loads first
//   (16 outstanding dwordx4/wave), scan in registers, then store 16 results.
//   nt stores kept (R3 cut WRITE 330->293 MB, FETCH halved via L3).

#define T_STEPS 16

typedef float f32x4 __attribute__((ext_vector_type(4)));

__global__ __launch_bounds__(256) void if_scan_kernel(
    const f32x4* __restrict__ x, f32x4* __restrict__ out, int n4) {
    int i = blockIdx.x * blockDim.x + threadIdx.x;
    if (i >= n4) return;

    f32x4 a[T_STEPS];
#pragma unroll
    for (int t = 0; t < T_STEPS; ++t) {
        a[t] = x[(size_t)t * (size_t)n4 + (size_t)i];
    }

    f32x4 v = (f32x4)(0.f);
#pragma unroll
    for (int t = 0; t < T_STEPS; ++t) {
        v += a[t];
        f32x4 s;
        s.x = (v.x >= 1.0f) ? 1.0f : 0.0f;
        s.y = (v.y >= 1.0f) ? 1.0f : 0.0f;
        s.z = (v.z >= 1.0f) ? 1.0f : 0.0f;
        s.w = (v.w >= 1.0f) ? 1.0f : 0.0f;
        v -= s;
        a[t] = s;  // reuse the register for the spike output
    }

#pragma unroll
    for (int t = 0; t < T_STEPS; ++t) {
        __builtin_nontemporal_store(a[t], &out[(size_t)t * (size_t)n4 + (size_t)i]);
    }
}

extern "C" void kernel_launch(void* const* d_in, const int* in_sizes, int n_in,
                              void* d_out, int out_size, void* d_ws, size_t ws_size,
                              hipStream_t stream) {
    const float* x = (const float*)d_in[0];
    float* out = (float*)d_out;

    int total = in_sizes[0];             // 16*32*128*32*32 = 67108864
    int per_step = total / T_STEPS;      // 4194304
    int n4 = per_step / 4;               // 1048576 float4 per timestep

    dim3 block(256);
    dim3 grid((n4 + block.x - 1) / block.x);   // 4096 blocks = 16/CU
    if_scan_kernel<<<grid, block, 0, stream>>>(
        (const f32x4*)x, (f32x4*)out, n4);
}